// Round 13
// baseline (462.769 us; speedup 1.0000x reference)
//
#include <hip/hip_runtime.h>

// GCN 2-layer forward on gfx950.
// R23 (= R22 resubmit; prior round was an infra failure, kernel untested):
//      gemm128 A-path de-LDS'd + B bank-conflict fix:
//      - A MFMA fragments loaded DIRECTLY to registers (fragment = 16
//        contiguous bytes at A[row][quad*8]; layout proven in R18). No A
//        ds_write -> no A-side conflicts, shorter staging chain, LDS 24->16KB.
//      - B LDS XOR-swizzle (T2/m201: linear glds dest + swizzled global
//        source col + same XOR on ds_read): 8-way -> 2-way (free) conflict.
//      Rest identical to R21 (initprep+lookback-scan preproc, int8 h, bf16
//      h2, nt-store hagg, XCD remap, gemm64 w2t-in-LDS).

typedef unsigned int u32;
typedef unsigned short u16;
typedef unsigned long long u64;
typedef __bf16 bf16x8 __attribute__((ext_vector_type(8)));
typedef float f32x4 __attribute__((ext_vector_type(4)));
typedef u32 u32x4 __attribute__((ext_vector_type(4)));

#define C_IN 512
#define C_HID 512
#define C_OUT 40
#define H_SCALE 24.0f
#define H_INV_SCALE (1.0f / 24.0f)

__device__ __forceinline__ float bf2f(u16 u) {
    u32 x = ((u32)u) << 16;
    return __builtin_bit_cast(float, x);
}
__device__ __forceinline__ u16 f2bf(float f) {
    u32 x = __builtin_bit_cast(u32, f);
    x += 0x7fffu + ((x >> 16) & 1u);   // RNE
    return (u16)(x >> 16);
}
__device__ __forceinline__ char q8(float v) {
    float c = fminf(fmaxf(v * H_SCALE, -127.f), 127.f);
    return (char)__float2int_rn(c);
}
__device__ __forceinline__ u32 pk2(float a, float b) {
    u16 lo = __builtin_bit_cast(u16, (__bf16)a);   // RNE, fuses to v_cvt_pk_bf16_f32
    u16 hi = __builtin_bit_cast(u16, (__bf16)b);
    return (u32)lo | ((u32)hi << 16);
}
__device__ __forceinline__ bf16x8 pkfrag(float4 a, float4 b) {
    u32x4 r;
    r.x = pk2(a.x, a.y); r.y = pk2(a.z, a.w);
    r.z = pk2(b.x, b.y); r.w = pk2(b.z, b.w);
    return __builtin_bit_cast(bf16x8, r);
}
__host__ __device__ __forceinline__ int imin(int a, int b) { return a < b ? a : b; }
__host__ __device__ __forceinline__ int imax(int a, int b) { return a > b ? a : b; }

__device__ __forceinline__ float ldf(const void* p, int i, int isbf) {
    return isbf ? bf2f(((const u16*)p)[i]) : ((const float*)p)[i];
}

// ---------------- initprep: flags + deg/cursor/state init + weight prep -----
__global__ __launch_bounds__(256) void k_initprep(
    const u32* __restrict__ x32, const int* __restrict__ ei,
    const void* __restrict__ W1, const void* __restrict__ b1,
    const void* __restrict__ W2, const void* __restrict__ b2,
    int* flags, int* deg, int* cursor, u64* state,
    u16* __restrict__ w1t, u16* __restrict__ w2t,
    float* __restrict__ b1f, float* __restrict__ b2f,
    int n, int nchunks) {
    __shared__ float tile[64][65];
    __shared__ int s_flags[2];
    int tid = threadIdx.x;
    // block-local dtype detection (no cross-block dependency)
    if (tid < 64) {
        int lane = tid;
        int z = (ei[2 * lane + 1] == 0) ? 1 : 0;
        u32 e = (x32[lane] >> 7) & 0xff;
        int v = (e >= 110 && e <= 133) ? 1 : 0;
        unsigned long long bz = __ballot(z);
        unsigned long long bv = __ballot(v);
        if (lane == 0) {
            s_flags[0] = (__popcll(bz) == 64) ? 2 : 1;
            s_flags[1] = (__popcll(bv) >= 48) ? 1 : 0;
        }
    }
    __syncthreads();
    int isbf = s_flags[1];
    int i0 = blockIdx.x * 256 + tid;
    int stride = gridDim.x * 256;
    if (blockIdx.x == 0 && tid == 0) { flags[0] = s_flags[0]; flags[1] = isbf; }
    if (i0 < n) { deg[i0] = 1; cursor[i0] = 0; }       // self-loop
    if (i0 < nchunks) state[i0] = 0ULL;
    // W1 transpose in 64x64 tiles (blocks 0..63)
    if (blockIdx.x < 64) {
        int t = blockIdx.x;
        int tr = t >> 3, tc = t & 7;
        int rr = tid >> 2, cq = (tid & 3) * 16;
#pragma unroll
        for (int c = 0; c < 16; ++c)
            tile[cq + c][rr] = ldf(W1, (tr * 64 + rr) * 512 + tc * 64 + cq + c, isbf);
        __syncthreads();
#pragma unroll
        for (int c = 0; c < 16; ++c)
            w1t[(size_t)(tc * 64 + rr) * 512 + tr * 64 + cq + c] = f2bf(tile[rr][cq + c]);
    }
    for (int i = i0; i < 64 * 512; i += stride) {
        int nn = i >> 9, k = i & 511;
        w2t[i] = (nn < C_OUT) ? f2bf(ldf(W2, k * C_OUT + nn, isbf)) : (u16)0;
    }
    if (i0 < C_HID) b1f[i0] = ldf(b1, i0, isbf);
    if (i0 < C_OUT) b2f[i0] = ldf(b2, i0, isbf);
}

__global__ void k_deg(const int* __restrict__ ei, const int* __restrict__ flags,
                      int* deg, int E, int ecap, int n) {
    int e = blockIdx.x * 256 + threadIdx.x;
    if (e >= E) return;
    int st = flags[0];
    int cap = ecap * st - 1;
    u32 d = (u32)ei[imin((E + e) * st, cap)];
    if (d < (u32)n) atomicAdd(&deg[d], 1);
}

// ---------------- single-kernel scan: dinv + exclusive offs (lookback) ------
__global__ __launch_bounds__(256) void k_scan(
    const int* __restrict__ deg, float* __restrict__ dinv, int* __restrict__ offs,
    u64* state, int n, int nchunks) {
    __shared__ int sh[256];
    __shared__ int s_prefix;
    int tid = threadIdx.x;
    int c = blockIdx.x;
    int i = c * 256 + tid;
    int dv = (i < n) ? deg[i] : 1;
    if (i < n) dinv[i] = rsqrtf((float)imax(dv, 1));
    int v = (i < n) ? dv - 1 : 0;
    sh[tid] = v;
    __syncthreads();
    for (int d = 1; d < 256; d <<= 1) {
        int add = (tid >= d) ? sh[tid - d] : 0;
        __syncthreads();
        sh[tid] += add;
        __syncthreads();
    }
    int total = sh[255];
    if (tid == 0) {
        atomicExch(&state[c], (1ULL << 62) | (u64)(u32)total);
        long long prefix = 0;
        int cc = c - 1;
        while (cc >= 0) {
            u64 s;
            do { s = atomicAdd(&state[cc], 0ULL); } while (s == 0ULL);
            prefix += (long long)(u32)s;
            if (s >> 63) break;
            --cc;
        }
        atomicExch(&state[c], (1ULL << 63) | (u64)(u32)(prefix + total));
        s_prefix = (int)prefix;
        if (c == nchunks - 1) offs[n] = (int)(prefix + total);
    }
    __syncthreads();
    int pfx = s_prefix;
    if (i < n) offs[i] = pfx + sh[tid] - v;   // exclusive
}

__global__ void k_sort(const int* __restrict__ ei, const int* __restrict__ flags,
                       const int* __restrict__ offs, int* cursor, int* csr,
                       int E, int ecap, int n) {
    int e = blockIdx.x * 256 + threadIdx.x;
    if (e >= E) return;
    int st = flags[0];
    int cap = ecap * st - 1;
    u32 d = (u32)ei[imin((E + e) * st, cap)];
    u32 s = (u32)ei[imin(e * st, cap)];
    if (d < (u32)n && s < (u32)n) {
        int pos = offs[d] + atomicAdd(&cursor[(int)d], 1);
        if ((u32)pos < (u32)E) csr[pos] = (int)s;
    }
}

// ---------------- GEMM1: 64x128 tile, A-in-regs, swizzled B LDS -------------
// Wave w: rows (w&1)*32..+31, cols (w>>1)*64..+63; acc[2][4].
// A: per K-half (32), 2 fragments direct to regs (fp32: 2xfloat4+cvt_pk).
// B: glds double-half staging; LDS[R][s] holds global col chunk s^((R>>1)&3)
//    (swizzled SOURCE, linear dest); ds_read applies same XOR -> 2-way only.
typedef __attribute__((address_space(1))) const u32 glds_src;
typedef __attribute__((address_space(3))) u32 glds_dst;

__global__ __launch_bounds__(256) void k_gemm128(
    const u16* __restrict__ xbf, const float* __restrict__ xf32,
    const int* __restrict__ flags, const u16* __restrict__ Bt,
    char* __restrict__ C, int M, int K, int ldc) {
    int isbf = flags[1];
    __shared__ __align__(16) u16 Bs0[128 * 32], Bs1[128 * 32];
    int tid = threadIdx.x;
    int wave = tid >> 6, lane = tid & 63;
    int quad = lane >> 4, lrow = lane & 15;
    int wrow = (wave & 1) * 32, wcol = (wave >> 1) * 64;

    // bijective XCD-chunk remap; 4 consecutive wg share an A row-panel
    int nwg = gridDim.x;
    int id = blockIdx.x;
    int q = nwg >> 3, r = nwg & 7;
    int xcd = id & 7, j8 = id >> 3;
    int wg = (xcd < r ? xcd * (q + 1) : r * (q + 1) + (xcd - r) * q) + j8;
    int row0 = (wg >> 2) * 64;
    int n0 = (wg & 3) * 128;

    // ---- B staging (swizzled source, linear glds dest) ----
    int lr = lane >> 2;            // 0..15 LDS row within 16-row group
    int lcq = lane & 3;            // 16B chunk slot in LDS row
    int skey = (lr >> 1) & 3;      // swizzle key (same for lr and lr+16)
    int sc = (lcq ^ skey) * 8;     // source col elems for this lane's slot
    int br = n0 + wave * 32 + lr;
    u16* Bs0_w = Bs0 + (wave * 32) * 32;
    u16* Bs1_w = Bs1 + (wave * 32) * 32;
    const u16* gB0b = Bt + (size_t)br * K + sc;
    const u16* gB1b = Bt + (size_t)(br + 16) * K + sc;

    // ---- A fragment pointers (direct-to-reg; layout proven in R18) ----
    int r0i = imin(row0 + wrow + lrow, M - 1);
    int r1i = imin(row0 + wrow + 16 + lrow, M - 1);
    const u16* aB0 = xbf + (size_t)r0i * K + quad * 8;
    const u16* aB1 = xbf + (size_t)r1i * K + quad * 8;
    const float* aF0 = xf32 + (size_t)r0i * K + quad * 8;
    const float* aF1 = xf32 + (size_t)r1i * K + quad * 8;

    // B read swizzle: key depends only on lrow (wave/j offsets vanish mod 4)
    int bkey = (lrow >> 1) & 3;
    int bq = (quad ^ bkey) * 8;

    f32x4 acc[2][4] = {};
    int kTiles = K >> 6;   // BK=64
    for (int kt = 0; kt < kTiles; ++kt) {
        int k0 = kt * 64;
        __builtin_amdgcn_global_load_lds((glds_src*)(gB0b + k0), (glds_dst*)Bs0_w, 16, 0, 0);
        __builtin_amdgcn_global_load_lds((glds_src*)(gB1b + k0), (glds_dst*)(Bs0_w + 16 * 32), 16, 0, 0);
        __builtin_amdgcn_global_load_lds((glds_src*)(gB0b + k0 + 32), (glds_dst*)Bs1_w, 16, 0, 0);
        __builtin_amdgcn_global_load_lds((glds_src*)(gB1b + k0 + 32), (glds_dst*)(Bs1_w + 16 * 32), 16, 0, 0);
        bf16x8 a00, a10, a01, a11;
        if (isbf) {
            a00 = *(const bf16x8*)(aB0 + k0);
            a10 = *(const bf16x8*)(aB1 + k0);
            a01 = *(const bf16x8*)(aB0 + k0 + 32);
            a11 = *(const bf16x8*)(aB1 + k0 + 32);
        } else {
            float4 u0 = *(const float4*)(aF0 + k0);
            float4 u1 = *(const float4*)(aF0 + k0 + 4);
            float4 u2 = *(const float4*)(aF1 + k0);
            float4 u3 = *(const float4*)(aF1 + k0 + 4);
            float4 u4 = *(const float4*)(aF0 + k0 + 32);
            float4 u5 = *(const float4*)(aF0 + k0 + 36);
            float4 u6 = *(const float4*)(aF1 + k0 + 32);
            float4 u7 = *(const float4*)(aF1 + k0 + 36);
            a00 = pkfrag(u0, u1);
            a10 = pkfrag(u2, u3);
            a01 = pkfrag(u4, u5);
            a11 = pkfrag(u6, u7);
        }
        __syncthreads();   // B staged (A loads complete into regs here too)
#pragma unroll
        for (int ko = 0; ko < 2; ++ko) {
            const u16* Bsrc = ko ? Bs1 : Bs0;
            bf16x8 aA = ko ? a01 : a00;
            bf16x8 aBv = ko ? a11 : a10;
            bf16x8 bfr[4];
#pragma unroll
            for (int j = 0; j < 4; ++j)
                bfr[j] = *(const bf16x8*)(Bsrc + (wcol + j * 16 + lrow) * 32 + bq);
#pragma unroll
            for (int j = 0; j < 4; ++j)
                acc[0][j] = __builtin_amdgcn_mfma_f32_16x16x32_bf16(aA, bfr[j],
                                                                    acc[0][j], 0, 0, 0);
#pragma unroll
            for (int j = 0; j < 4; ++j)
                acc[1][j] = __builtin_amdgcn_mfma_f32_16x16x32_bf16(aBv, bfr[j],
                                                                    acc[1][j], 0, 0, 0);
        }
        __syncthreads();   // guard B LDS reuse
    }
#pragma unroll
    for (int i = 0; i < 2; ++i)
#pragma unroll
        for (int j = 0; j < 4; ++j)
#pragma unroll
            for (int r2 = 0; r2 < 4; ++r2) {
                int row = row0 + wrow + i * 16 + quad * 4 + r2;
                int col = n0 + wcol + j * 16 + lrow;
                if (row < M) C[(size_t)row * ldc + col] = q8(acc[i][j][r2]);
            }
}

// ---------------- GEMM2: w2t-in-LDS, barrier-free A stream, bf16 out --------
#define B2ROW 520
__global__ __launch_bounds__(256) void k_gemm64(
    const u16* __restrict__ A, const u16* __restrict__ Bt, u16* __restrict__ Cout,
    int M, int K, int Ncols, int ldc) {
    __shared__ __align__(16) u16 Bsh[48 * B2ROW];
    int tid = threadIdx.x;
    int wave = tid >> 6, lane = tid & 63;
    int quad = lane >> 4, lrow = lane & 15;

    for (int i = tid; i < 48 * 64; i += 256) {
        int rw = i >> 6, cv = (i & 63) * 8;
        *(uint4*)(Bsh + rw * B2ROW + cv) = *(const uint4*)(Bt + (size_t)rw * 512 + cv);
    }
    __syncthreads();

    int row0 = blockIdx.x * 128 + wave * 32;
    int r0 = imin(row0 + lrow, M - 1);
    int r1 = imin(row0 + 16 + lrow, M - 1);
    const u16* a0p = A + (size_t)r0 * K + quad * 8;
    const u16* a1p = A + (size_t)r1 * K + quad * 8;
    const u16* b0p = Bsh + (0 * 16 + lrow) * B2ROW + quad * 8;
    const u16* b1p = Bsh + (1 * 16 + lrow) * B2ROW + quad * 8;
    const u16* b2p = Bsh + (2 * 16 + lrow) * B2ROW + quad * 8;

    f32x4 c00 = {}, c01 = {}, c02 = {};
    f32x4 c10 = {}, c11 = {}, c12 = {};
#pragma unroll 4
    for (int k0 = 0; k0 < C_HID; k0 += 32) {
        bf16x8 a0 = *(const bf16x8*)(a0p + k0);
        bf16x8 a1 = *(const bf16x8*)(a1p + k0);
        bf16x8 b0 = *(const bf16x8*)(b0p + k0);
        bf16x8 b1 = *(const bf16x8*)(b1p + k0);
        bf16x8 b2 = *(const bf16x8*)(b2p + k0);
        c00 = __builtin_amdgcn_mfma_f32_16x16x32_bf16(a0, b0, c00, 0, 0, 0);
        c01 = __builtin_amdgcn_mfma_f32_16x16x32_bf16(a0, b1, c01, 0, 0, 0);
        c02 = __builtin_amdgcn_mfma_f32_16x16x32_bf16(a0, b2, c02, 0, 0, 0);
        c10 = __builtin_amdgcn_mfma_f32_16x16x32_bf16(a1, b0, c10, 0, 0, 0);
        c11 = __builtin_amdgcn_mfma_f32_16x16x32_bf16(a1, b1, c11, 0, 0, 0);
        c12 = __builtin_amdgcn_mfma_f32_16x16x32_bf16(a1, b2, c12, 0, 0, 0);
    }
    f32x4 cc[2][3] = {{c00, c01, c02}, {c10, c11, c12}};
#pragma unroll
    for (int i = 0; i < 2; ++i)
#pragma unroll
        for (int t = 0; t < 3; ++t)
#pragma unroll
            for (int r = 0; r < 4; ++r) {
                int row = row0 + i * 16 + quad * 4 + r;
                int col = t * 16 + lrow;
                if (row < M && col < Ncols)
                    Cout[(size_t)row * ldc + col] = f2bf(cc[i][t][r]);
            }
}

// ---------------- agg1: hagg = ReLU(Anorm*h + b1), int8 in, bf16 out ----------------
__device__ __forceinline__ void accum8i(float* acc, uint2 p, float w) {
    int lo = (int)p.x, hi = (int)p.y;
    acc[0] += w * (float)(signed char)(lo);
    acc[1] += w * (float)(signed char)(lo >> 8);
    acc[2] += w * (float)(signed char)(lo >> 16);
    acc[3] += w * (float)(signed char)(lo >> 24);
    acc[4] += w * (float)(signed char)(hi);
    acc[5] += w * (float)(signed char)(hi >> 8);
    acc[6] += w * (float)(signed char)(hi >> 16);
    acc[7] += w * (float)(signed char)(hi >> 24);
}

__global__ __launch_bounds__(256) void k_agg1(
    const char* __restrict__ hq, const int* __restrict__ csr, const int* __restrict__ offs,
    const float* __restrict__ dinv, const float* __restrict__ b1f,
    u16* __restrict__ out, int n, int Etot) {
    int wave = threadIdx.x >> 6, lane = threadIdx.x & 63;
    int v = blockIdx.x * 4 + wave;
    if (v >= n) return;
    float dv = dinv[v];
    float wself = dv * dv * H_INV_SCALE;

    float acc[8] = {0.f, 0.f, 0.f, 0.f, 0.f, 0.f, 0.f, 0.f};
    uint2 hs = *(const uint2*)(hq + (size_t)v * C_HID + lane * 8);
    accum8i(acc, hs, wself);

    int e0 = imax(0, imin(offs[v], Etot));
    int e1 = imax(e0, imin(offs[v + 1], Etot));
    for (int base = e0; base < e1; base += 64) {
        int cnt = imin(64, e1 - base);
        int sreg = 0; float wreg = 0.f;
        if (lane < cnt) {
            u32 s = (u32)csr[base + lane];
            s = (s < (u32)n) ? s : 0u;
            sreg = (int)s;
            wreg = dv * dinv[s] * H_INV_SCALE;
        }
        int j = 0;
        for (; j + 16 <= cnt; j += 16) {
            int ss[16]; float ww[16]; uint2 pp[16];
#pragma unroll
            for (int t = 0; t < 16; ++t) {
                ss[t] = __shfl(sreg, j + t);
                ww[t] = __shfl(wreg, j + t);
            }
#pragma unroll
            for (int t = 0; t < 16; ++t)
                pp[t] = *(const uint2*)(hq + (size_t)ss[t] * C_HID + lane * 8);
#pragma unroll
            for (int t = 0; t < 16; ++t) accum8i(acc, pp[t], ww[t]);
        }
        for (; j + 8 <= cnt; j += 8) {
            int ss[8]; float ww[8]; uint2 pp[8];
#pragma unroll
            for (int t = 0; t < 8; ++t) {
                ss[t] = __shfl(sreg, j + t);
                ww[t] = __shfl(wreg, j + t);
            }
#pragma unroll
            for (int t = 0; t < 8; ++t)
                pp[t] = *(const uint2*)(hq + (size_t)ss[t] * C_HID + lane * 8);
#pragma unroll
            for (int t = 0; t < 8; ++t) accum8i(acc, pp[t], ww[t]);
        }
        for (; j + 4 <= cnt; j += 4) {
            int ss[4]; float ww[4]; uint2 pp[4];
#pragma unroll
            for (int t = 0; t < 4; ++t) {
                ss[t] = __shfl(sreg, j + t);
                ww[t] = __shfl(wreg, j + t);
            }
#pragma unroll
            for (int t = 0; t < 4; ++t)
                pp[t] = *(const uint2*)(hq + (size_t)ss[t] * C_HID + lane * 8);
#pragma unroll
            for (int t = 0; t < 4; ++t) accum8i(acc, pp[t], ww[t]);
        }
        for (; j < cnt; ++j) {
            int sj = __shfl(sreg, j);
            float wj = __shfl(wreg, j);
            uint2 pj = *(const uint2*)(hq + (size_t)sj * C_HID + lane * 8);
            accum8i(acc, pj, wj);
        }
    }

    float4 ba = *(const float4*)(b1f + lane * 8);
    float4 bb = *(const float4*)(b1f + lane * 8 + 4);
    float r0 = fmaxf(acc[0] + ba.x, 0.f), r1 = fmaxf(acc[1] + ba.y, 0.f);
    float r2 = fmaxf(acc[2] + ba.z, 0.f), r3 = fmaxf(acc[3] + ba.w, 0.f);
    float r4 = fmaxf(acc[4] + bb.x, 0.f), r5 = fmaxf(acc[5] + bb.y, 0.f);
    float r6 = fmaxf(acc[6] + bb.z, 0.f), r7 = fmaxf(acc[7] + bb.w, 0.f);
    u32x4 o;
    o.x = (u32)f2bf(r0) | ((u32)f2bf(r1) << 16);
    o.y = (u32)f2bf(r2) | ((u32)f2bf(r3) << 16);
    o.z = (u32)f2bf(r4) | ((u32)f2bf(r5) << 16);
    o.w = (u32)f2bf(r6) | ((u32)f2bf(r7) << 16);
    // nontemporal: don't let the 50MB output stream evict h from L2
    __builtin_nontemporal_store(o, (u32x4*)(out + (size_t)v * C_HID + lane * 8));
}

// ---------------- agg2 + bias + log_softmax: bf16 h2, 24 edges in flight ----------------
__global__ __launch_bounds__(256) void k_agg2(
    const u16* __restrict__ h2, const int* __restrict__ csr, const int* __restrict__ offs,
    const float* __restrict__ dinv, const float* __restrict__ b2f,
    const int* __restrict__ flags, void* __restrict__ out, int n, int Etot) {
    int wave = threadIdx.x >> 6, lane = threadIdx.x & 63;
    int v = blockIdx.x * 4 + wave;
    if (v >= n) return;
    float dv = dinv[v];

    int g = lane / 10;            // 0..6
    int f4 = lane - g * 10;       // 0..9
    bool active = (g < 6);

    float4 acc = make_float4(0.f, 0.f, 0.f, 0.f);
    if (g == 0) {
        uint2 pv = *(const uint2*)(h2 + (size_t)v * C_OUT + f4 * 4);
        float w = dv * dv;
        acc.x = w * bf2f((u16)pv.x); acc.y = w * bf2f((u16)(pv.x >> 16));
        acc.z = w * bf2f((u16)pv.y); acc.w = w * bf2f((u16)(pv.y >> 16));
    }

    int e0 = imax(0, imin(offs[v], Etot));
    int e1 = imax(e0, imin(offs[v + 1], Etot));
    for (int base = e0; base < e1; base += 64) {
        int cnt = imin(64, e1 - base);
        int sreg = 0; float wreg = 0.f;
        if (lane < cnt) {
            u32 s = (u32)csr[base + lane];
            s = (s < (u32)n) ? s : 0u;
            sreg = (int)s;
            wreg = dv * dinv[s];
        }
        for (int j = 0; j < cnt; j += 24) {
            uint2 p[4]; float w4[4];
#pragma unroll
            for (int t = 0; t < 4; ++t) {
                int jj = j + t * 6 + g;
                int idx = imin(jj, cnt - 1);
                int sj = __shfl(sreg, idx);
                float wj = __shfl(wreg, idx);
                w4[t] = (active && jj < cnt) ? wj : 0.f;
                p[t] = make_uint2(0, 0);
                if (active) p[t] = *(const uint2*)(h2 + (size_t)sj * C_OUT + f4 * 4);
            }
#pragma unroll
            for (int t = 0; t < 4; ++t) {
                acc.x += w4[t] * bf2f((u16)p[t].x);
                acc.y += w4[t] * bf2f((u16)(p[t].x >> 16));
                acc.z += w4[t] * bf2f((u16)p[t].y);
                acc.w += w4[t] * bf2f((u16)(p[t].y >> 16));
            }
        }
    }

    float4 t;
    t.x = __shfl(acc.x, lane + 30); t.y = __shfl(acc.y, lane + 30);
    t.z = __shfl(acc.z, lane + 30); t.w = __shfl(acc.w, lane + 30);
    if (lane < 30) { acc.x += t.x; acc.y += t.y; acc.z += t.z; acc.w += t.w; }
    float4 t1, t2;
    t1.x = __shfl(acc.x, lane + 10); t1.y = __shfl(acc.y, lane + 10);
    t1.z = __shfl(acc.z, lane + 10); t1.w = __shfl(acc.w, lane + 10);
    t2.x = __shfl(acc.x, lane + 20); t2.y = __shfl(acc.y, lane + 20);
    t2.z = __shfl(acc.z, lane + 20); t2.w = __shfl(acc.w, lane + 20);
    if (lane < 10) {
        acc.x += t1.x + t2.x; acc.y += t1.y + t2.y;
        acc.z += t1.z + t2.z; acc.w += t1.w + t2.w;
        acc.x += b2f[f4 * 4 + 0]; acc.y += b2f[f4 * 4 + 1];
        acc.z += b2f[f4 * 4 + 2]; acc.w += b2f[f4 * 4 + 3];
    }

    float m = -1e30f;
    if (lane < 10) m = fmaxf(fmaxf(acc.x, acc.y), fmaxf(acc.z, acc.w));
    for (int off = 32; off > 0; off >>= 1) m = fmaxf(m, __shfl_xor(m, off));
    float s = 0.f;
    if (lane < 10)
        s = expf(acc.x - m) + expf(acc.y - m) + expf(acc.z - m) + expf(acc.w - m);
    for (int off = 32; off > 0; off >>= 1) s += __shfl_xor(s, off);
    if (lane < 10) {
        float ls = m + logf(s);
        if (flags[1]) {
            ushort4 o;
            o.x = f2bf(acc.x - ls); o.y = f2bf(acc.y - ls);
            o.z = f2bf(acc.z - ls); o.w = f2bf(acc.w - ls);
            *(ushort4*)((u16*)out + (size_t)v * C_OUT + f4 * 4) = o;
        } else {
            float4 o = make_float4(acc.x - ls, acc.y - ls, acc.z - ls, acc.w - ls);
            *(float4*)((float*)out + (size_t)v * C_OUT + f4 * 4) = o;
        }
    }
}

// ---------------- launch ----------------

extern "C" void kernel_launch(void* const* d_in, const int* in_sizes, int n_in,
                              void* d_out, int out_size, void* d_ws, size_t ws_size,
                              hipStream_t stream) {
    const void* x = d_in[0];
    const int* ei = (const int*)d_in[1];
    const void* W1 = d_in[2];
    const void* b1 = d_in[3];
    const void* W2 = d_in[4];
    const void* b2 = d_in[5];

    const int N = out_size / C_OUT;
    const int Mx = in_sizes[0] / C_IN;
    const int M = (N < Mx) ? N : Mx;
    const int ECAP = in_sizes[1];
    const int E = ECAP / 2;

    char* p = (char*)d_ws;
    size_t used = 0;
    auto carve = [&](size_t bytes) -> void* {
        void* r = (void*)p;
        size_t b = (bytes + 255) & ~(size_t)255;
        p += b; used += b;
        return r;
    };
    int* flags = (int*)carve(256);
    int* deg = (int*)carve((size_t)N * 4);
    int* cursor = (int*)carve((size_t)N * 4);
    float* dinv = (float*)carve((size_t)N * 4);
    int* offs = (int*)carve((size_t)(N + 1) * 4);
    u64* state = (u64*)carve(4096);
    int* csr = (int*)carve((size_t)E * 4);
    u16* w1t = (u16*)carve((size_t)C_HID * C_IN * 2);
    u16* w2t = (u16*)carve((size_t)64 * C_HID * 2);
    float* b1f = (float*)carve(C_HID * 4);
    float* b2f = (float*)carve(256);
    u16* bufA = (u16*)carve((size_t)N * C_HID * 2);   // hagg
    u16* bufB = (u16*)carve((size_t)N * C_HID * 2);   // h_i8, then h2 (bf16)
    if (used > ws_size) return;

    char* h_i8 = (char*)bufB;
    u16* hagg = bufA;
    u16* h2 = bufB;

    const int NB = (N + 255) / 256;
    const int EB = (E + 255) / 256;

    k_initprep<<<NB, 256, 0, stream>>>((const u32*)x, ei, W1, b1, W2, b2,
                                       flags, deg, cursor, state,
                                       w1t, w2t, b1f, b2f, N, NB);
    k_deg<<<EB, 256, 0, stream>>>(ei, flags, deg, E, ECAP, N);
    k_scan<<<NB, 256, 0, stream>>>(deg, dinv, offs, state, N, NB);
    k_sort<<<EB, 256, 0, stream>>>(ei, flags, offs, cursor, csr, E, ECAP, N);

    int nbx = (M + 63) / 64;
    k_gemm128<<<nbx * 4, 256, 0, stream>>>((const u16*)x, (const float*)x, flags,
                                           w1t, h_i8, M, C_IN, C_HID);

    k_agg1<<<(N + 3) / 4, 256, 0, stream>>>(h_i8, csr, offs, dinv, b1f, hagg, N, E);

    k_gemm64<<<(M + 127) / 128, 256, 0, stream>>>(hagg, w2t, h2, N, C_HID, C_OUT, C_OUT);

    k_agg2<<<(N + 3) / 4, 256, 0, stream>>>(h2, csr, offs, dinv, b2f, flags, d_out, N, E);
}

// Round 14
// 407.638 us; speedup vs baseline: 1.1352x; 1.1352x over previous
//
#include <hip/hip_runtime.h>

// GCN 2-layer forward on gfx950.
// R24: base = R21 (best measured 399us). gemm128 keeps the R16 A-through-LDS
//      structure (every de-LDS attempt R18/R19/R23 lost to register-miser
//      scheduling) but adds the R23-verified XOR swizzle WITHOUT changing the
//      staging structure: LDS[row][slot] = chunk slot^(row&3) (fp32 A:
//      swizzled ds_write dest; bf16 A + B glds: swizzled source chunk);
//      fragment reads use quad^(lrow&3). 8-way read conflicts -> 4-way.
//      Rest identical to R21.

typedef unsigned int u32;
typedef unsigned short u16;
typedef unsigned long long u64;
typedef __bf16 bf16x8 __attribute__((ext_vector_type(8)));
typedef float f32x4 __attribute__((ext_vector_type(4)));
typedef u32 u32x4 __attribute__((ext_vector_type(4)));

#define C_IN 512
#define C_HID 512
#define C_OUT 40
#define H_SCALE 24.0f
#define H_INV_SCALE (1.0f / 24.0f)

__device__ __forceinline__ float bf2f(u16 u) {
    u32 x = ((u32)u) << 16;
    return __builtin_bit_cast(float, x);
}
__device__ __forceinline__ u16 f2bf(float f) {
    u32 x = __builtin_bit_cast(u32, f);
    x += 0x7fffu + ((x >> 16) & 1u);   // RNE
    return (u16)(x >> 16);
}
__device__ __forceinline__ char q8(float v) {
    float c = fminf(fmaxf(v * H_SCALE, -127.f), 127.f);
    return (char)__float2int_rn(c);
}
__device__ __forceinline__ u32 pk2(float a, float b) {
    u16 lo = __builtin_bit_cast(u16, (__bf16)a);
    u16 hi = __builtin_bit_cast(u16, (__bf16)b);
    return (u32)lo | ((u32)hi << 16);
}
__device__ __forceinline__ u32x4 pk8(float4 a, float4 b) {
    u32x4 r;
    r.x = pk2(a.x, a.y); r.y = pk2(a.z, a.w);
    r.z = pk2(b.x, b.y); r.w = pk2(b.z, b.w);
    return r;
}
__host__ __device__ __forceinline__ int imin(int a, int b) { return a < b ? a : b; }
__host__ __device__ __forceinline__ int imax(int a, int b) { return a > b ? a : b; }

__device__ __forceinline__ float ldf(const void* p, int i, int isbf) {
    return isbf ? bf2f(((const u16*)p)[i]) : ((const float*)p)[i];
}

// ---------------- initprep: flags + deg/cursor/state init + weight prep -----
__global__ __launch_bounds__(256) void k_initprep(
    const u32* __restrict__ x32, const int* __restrict__ ei,
    const void* __restrict__ W1, const void* __restrict__ b1,
    const void* __restrict__ W2, const void* __restrict__ b2,
    int* flags, int* deg, int* cursor, u64* state,
    u16* __restrict__ w1t, u16* __restrict__ w2t,
    float* __restrict__ b1f, float* __restrict__ b2f,
    int n, int nchunks) {
    __shared__ float tile[64][65];
    __shared__ int s_flags[2];
    int tid = threadIdx.x;
    if (tid < 64) {
        int lane = tid;
        int z = (ei[2 * lane + 1] == 0) ? 1 : 0;
        u32 e = (x32[lane] >> 7) & 0xff;
        int v = (e >= 110 && e <= 133) ? 1 : 0;
        unsigned long long bz = __ballot(z);
        unsigned long long bv = __ballot(v);
        if (lane == 0) {
            s_flags[0] = (__popcll(bz) == 64) ? 2 : 1;
            s_flags[1] = (__popcll(bv) >= 48) ? 1 : 0;
        }
    }
    __syncthreads();
    int isbf = s_flags[1];
    int i0 = blockIdx.x * 256 + tid;
    int stride = gridDim.x * 256;
    if (blockIdx.x == 0 && tid == 0) { flags[0] = s_flags[0]; flags[1] = isbf; }
    if (i0 < n) { deg[i0] = 1; cursor[i0] = 0; }       // self-loop
    if (i0 < nchunks) state[i0] = 0ULL;
    if (blockIdx.x < 64) {
        int t = blockIdx.x;
        int tr = t >> 3, tc = t & 7;
        int rr = tid >> 2, cq = (tid & 3) * 16;
#pragma unroll
        for (int c = 0; c < 16; ++c)
            tile[cq + c][rr] = ldf(W1, (tr * 64 + rr) * 512 + tc * 64 + cq + c, isbf);
        __syncthreads();
#pragma unroll
        for (int c = 0; c < 16; ++c)
            w1t[(size_t)(tc * 64 + rr) * 512 + tr * 64 + cq + c] = f2bf(tile[rr][cq + c]);
    }
    for (int i = i0; i < 64 * 512; i += stride) {
        int nn = i >> 9, k = i & 511;
        w2t[i] = (nn < C_OUT) ? f2bf(ldf(W2, k * C_OUT + nn, isbf)) : (u16)0;
    }
    if (i0 < C_HID) b1f[i0] = ldf(b1, i0, isbf);
    if (i0 < C_OUT) b2f[i0] = ldf(b2, i0, isbf);
}

__global__ void k_deg(const int* __restrict__ ei, const int* __restrict__ flags,
                      int* deg, int E, int ecap, int n) {
    int e = blockIdx.x * 256 + threadIdx.x;
    if (e >= E) return;
    int st = flags[0];
    int cap = ecap * st - 1;
    u32 d = (u32)ei[imin((E + e) * st, cap)];
    if (d < (u32)n) atomicAdd(&deg[d], 1);
}

// ---------------- single-kernel scan: dinv + exclusive offs (lookback) ------
__global__ __launch_bounds__(256) void k_scan(
    const int* __restrict__ deg, float* __restrict__ dinv, int* __restrict__ offs,
    u64* state, int n, int nchunks) {
    __shared__ int sh[256];
    __shared__ int s_prefix;
    int tid = threadIdx.x;
    int c = blockIdx.x;
    int i = c * 256 + tid;
    int dv = (i < n) ? deg[i] : 1;
    if (i < n) dinv[i] = rsqrtf((float)imax(dv, 1));
    int v = (i < n) ? dv - 1 : 0;
    sh[tid] = v;
    __syncthreads();
    for (int d = 1; d < 256; d <<= 1) {
        int add = (tid >= d) ? sh[tid - d] : 0;
        __syncthreads();
        sh[tid] += add;
        __syncthreads();
    }
    int total = sh[255];
    if (tid == 0) {
        atomicExch(&state[c], (1ULL << 62) | (u64)(u32)total);
        long long prefix = 0;
        int cc = c - 1;
        while (cc >= 0) {
            u64 s;
            do { s = atomicAdd(&state[cc], 0ULL); } while (s == 0ULL);
            prefix += (long long)(u32)s;
            if (s >> 63) break;
            --cc;
        }
        atomicExch(&state[c], (1ULL << 63) | (u64)(u32)(prefix + total));
        s_prefix = (int)prefix;
        if (c == nchunks - 1) offs[n] = (int)(prefix + total);
    }
    __syncthreads();
    int pfx = s_prefix;
    if (i < n) offs[i] = pfx + sh[tid] - v;   // exclusive
}

__global__ void k_sort(const int* __restrict__ ei, const int* __restrict__ flags,
                       const int* __restrict__ offs, int* cursor, int* csr,
                       int E, int ecap, int n) {
    int e = blockIdx.x * 256 + threadIdx.x;
    if (e >= E) return;
    int st = flags[0];
    int cap = ecap * st - 1;
    u32 d = (u32)ei[imin((E + e) * st, cap)];
    u32 s = (u32)ei[imin(e * st, cap)];
    if (d < (u32)n && s < (u32)n) {
        int pos = offs[d] + atomicAdd(&cursor[(int)d], 1);
        if ((u32)pos < (u32)E) csr[pos] = (int)s;
    }
}

// ---------------- GEMM1: 64x128 tile, BK=64, split-half LDS + XOR swizzle ---
// LDS[row][slot] = chunk slot^(row&3) (chunk = 16B). fp32 A: swizzled
// ds_write dest; bf16 A + B glds: swizzled global source. Fragment reads at
// slot quad^(lrow&3). Structure otherwise identical to R16/R21 (76us known).
typedef __attribute__((address_space(1))) const u32 glds_src;
typedef __attribute__((address_space(3))) u32 glds_dst;

__global__ __launch_bounds__(256) void k_gemm128(
    const u16* __restrict__ xbf, const float* __restrict__ xf32,
    const int* __restrict__ flags, const u16* __restrict__ Bt,
    char* __restrict__ C, int M, int K, int ldc) {
    int isbf = flags[1];
    __shared__ __align__(16) u16 As0[64 * 32], As1[64 * 32];
    __shared__ __align__(16) u16 Bs0[128 * 32], Bs1[128 * 32];
    int tid = threadIdx.x;
    int wave = tid >> 6, lane = tid & 63;
    int quad = lane >> 4, lrow = lane & 15;
    int wrow = (wave & 1) * 32, wcol = (wave >> 1) * 64;

    int nwg = gridDim.x;
    int id = blockIdx.x;
    int q = nwg >> 3, r = nwg & 7;
    int xcd = id & 7, j8 = id >> 3;
    int wg = (xcd < r ? xcd * (q + 1) : r * (q + 1) + (xcd - r) * q) + j8;
    int row0 = (wg >> 2) * 64;
    int n0 = (wg & 3) * 128;

    int lr = lane >> 2;            // 0..15 row within 16-row staging group
    int lcq = lane & 3;            // 16B chunk slot
    int key = lr & 3;              // swizzle key per LDS row
    int lc = (lane & 3) * 8;       // linear col elems (fp32 A source)
    int scs = (lcq ^ key) * 8;     // swizzled source col elems (glds paths)
    int ar = row0 + wave * 16 + lr;
    int br = n0 + wave * 32 + lr;
    u16* As0_w = As0 + (wave * 16) * 32;
    u16* As1_w = As1 + (wave * 16) * 32;
    u16* Bs0_w = Bs0 + (wave * 32) * 32;
    u16* Bs1_w = Bs1 + (wave * 32) * 32;

    f32x4 acc[2][4] = {};
    int kTiles = K >> 6;   // BK=64
    int a0 = imin(ar, M - 1);
    int rdq = (quad ^ (lrow & 3)) * 8;   // swizzled read slot (elems)
    for (int kt = 0; kt < kTiles; ++kt) {
        int k0 = kt * 64;
        if (isbf) {
            const u16* gA0 = xbf + (size_t)a0 * K + k0 + scs;
            __builtin_amdgcn_global_load_lds((glds_src*)gA0, (glds_dst*)As0_w, 16, 0, 0);
            __builtin_amdgcn_global_load_lds((glds_src*)(gA0 + 32), (glds_dst*)As1_w, 16, 0, 0);
        } else {
            const float* f0 = xf32 + (size_t)a0 * K + k0 + lc;
            float4 u0 = *(const float4*)(f0);
            float4 u1 = *(const float4*)(f0 + 4);
            float4 u2 = *(const float4*)(f0 + 32);
            float4 u3 = *(const float4*)(f0 + 36);
            int dsl = (lcq ^ key) * 8;   // swizzled ds_write dest slot
            *(u32x4*)(As0_w + lr * 32 + dsl) = pk8(u0, u1);
            *(u32x4*)(As1_w + lr * 32 + dsl) = pk8(u2, u3);
        }
        const u16* gB0 = Bt + (size_t)br * K + k0 + scs;
        const u16* gB1 = Bt + (size_t)(br + 16) * K + k0 + scs;
        __builtin_amdgcn_global_load_lds((glds_src*)gB0, (glds_dst*)Bs0_w, 16, 0, 0);
        __builtin_amdgcn_global_load_lds((glds_src*)gB1, (glds_dst*)(Bs0_w + 16 * 32), 16, 0, 0);
        __builtin_amdgcn_global_load_lds((glds_src*)(gB0 + 32), (glds_dst*)Bs1_w, 16, 0, 0);
        __builtin_amdgcn_global_load_lds((glds_src*)(gB1 + 32), (glds_dst*)(Bs1_w + 16 * 32), 16, 0, 0);
        __syncthreads();
#pragma unroll
        for (int ko = 0; ko < 2; ++ko) {
            const u16* Asrc = ko ? As1 : As0;
            const u16* Bsrc = ko ? Bs1 : Bs0;
            bf16x8 af[2], bfr[4];
#pragma unroll
            for (int i = 0; i < 2; ++i)
                af[i] = *(const bf16x8*)(Asrc + (wrow + i * 16 + lrow) * 32 + rdq);
#pragma unroll
            for (int j = 0; j < 4; ++j)
                bfr[j] = *(const bf16x8*)(Bsrc + (wcol + j * 16 + lrow) * 32 + rdq);
#pragma unroll
            for (int i = 0; i < 2; ++i)
#pragma unroll
                for (int j = 0; j < 4; ++j)
                    acc[i][j] = __builtin_amdgcn_mfma_f32_16x16x32_bf16(af[i], bfr[j],
                                                                        acc[i][j], 0, 0, 0);
        }
        __syncthreads();
    }
#pragma unroll
    for (int i = 0; i < 2; ++i)
#pragma unroll
        for (int j = 0; j < 4; ++j)
#pragma unroll
            for (int r2 = 0; r2 < 4; ++r2) {
                int row = row0 + wrow + i * 16 + quad * 4 + r2;
                int col = n0 + wcol + j * 16 + lrow;
                if (row < M) C[(size_t)row * ldc + col] = q8(acc[i][j][r2]);
            }
}

// ---------------- GEMM2: w2t-in-LDS, barrier-free A stream, bf16 out --------
#define B2ROW 520
__global__ __launch_bounds__(256) void k_gemm64(
    const u16* __restrict__ A, const u16* __restrict__ Bt, u16* __restrict__ Cout,
    int M, int K, int Ncols, int ldc) {
    __shared__ __align__(16) u16 Bsh[48 * B2ROW];
    int tid = threadIdx.x;
    int wave = tid >> 6, lane = tid & 63;
    int quad = lane >> 4, lrow = lane & 15;

    for (int i = tid; i < 48 * 64; i += 256) {
        int rw = i >> 6, cv = (i & 63) * 8;
        *(uint4*)(Bsh + rw * B2ROW + cv) = *(const uint4*)(Bt + (size_t)rw * 512 + cv);
    }
    __syncthreads();

    int row0 = blockIdx.x * 128 + wave * 32;
    int r0 = imin(row0 + lrow, M - 1);
    int r1 = imin(row0 + 16 + lrow, M - 1);
    const u16* a0p = A + (size_t)r0 * K + quad * 8;
    const u16* a1p = A + (size_t)r1 * K + quad * 8;
    const u16* b0p = Bsh + (0 * 16 + lrow) * B2ROW + quad * 8;
    const u16* b1p = Bsh + (1 * 16 + lrow) * B2ROW + quad * 8;
    const u16* b2p = Bsh + (2 * 16 + lrow) * B2ROW + quad * 8;

    f32x4 c00 = {}, c01 = {}, c02 = {};
    f32x4 c10 = {}, c11 = {}, c12 = {};
#pragma unroll 4
    for (int k0 = 0; k0 < C_HID; k0 += 32) {
        bf16x8 a0 = *(const bf16x8*)(a0p + k0);
        bf16x8 a1 = *(const bf16x8*)(a1p + k0);
        bf16x8 b0 = *(const bf16x8*)(b0p + k0);
        bf16x8 b1 = *(const bf16x8*)(b1p + k0);
        bf16x8 b2 = *(const bf16x8*)(b2p + k0);
        c00 = __builtin_amdgcn_mfma_f32_16x16x32_bf16(a0, b0, c00, 0, 0, 0);
        c01 = __builtin_amdgcn_mfma_f32_16x16x32_bf16(a0, b1, c01, 0, 0, 0);
        c02 = __builtin_amdgcn_mfma_f32_16x16x32_bf16(a0, b2, c02, 0, 0, 0);
        c10 = __builtin_amdgcn_mfma_f32_16x16x32_bf16(a1, b0, c10, 0, 0, 0);
        c11 = __builtin_amdgcn_mfma_f32_16x16x32_bf16(a1, b1, c11, 0, 0, 0);
        c12 = __builtin_amdgcn_mfma_f32_16x16x32_bf16(a1, b2, c12, 0, 0, 0);
    }
    f32x4 cc[2][3] = {{c00, c01, c02}, {c10, c11, c12}};
#pragma unroll
    for (int i = 0; i < 2; ++i)
#pragma unroll
        for (int t = 0; t < 3; ++t)
#pragma unroll
            for (int r = 0; r < 4; ++r) {
                int row = row0 + i * 16 + quad * 4 + r;
                int col = t * 16 + lrow;
                if (row < M && col < Ncols)
                    Cout[(size_t)row * ldc + col] = f2bf(cc[i][t][r]);
            }
}

// ---------------- agg1: hagg = ReLU(Anorm*h + b1), int8 in, bf16 out ----------------
__device__ __forceinline__ void accum8i(float* acc, uint2 p, float w) {
    int lo = (int)p.x, hi = (int)p.y;
    acc[0] += w * (float)(signed char)(lo);
    acc[1] += w * (float)(signed char)(lo >> 8);
    acc[2] += w * (float)(signed char)(lo >> 16);
    acc[3] += w * (float)(signed char)(lo >> 24);
    acc[4] += w * (float)(signed char)(hi);
    acc[5] += w * (float)(signed char)(hi >> 8);
    acc[6] += w * (float)(signed char)(hi >> 16);
    acc[7] += w * (float)(signed char)(hi >> 24);
}

__global__ __launch_bounds__(256) void k_agg1(
    const char* __restrict__ hq, const int* __restrict__ csr, const int* __restrict__ offs,
    const float* __restrict__ dinv, const float* __restrict__ b1f,
    u16* __restrict__ out, int n, int Etot) {
    int wave = threadIdx.x >> 6, lane = threadIdx.x & 63;
    int v = blockIdx.x * 4 + wave;
    if (v >= n) return;
    float dv = dinv[v];
    float wself = dv * dv * H_INV_SCALE;

    float acc[8] = {0.f, 0.f, 0.f, 0.f, 0.f, 0.f, 0.f, 0.f};
    uint2 hs = *(const uint2*)(hq + (size_t)v * C_HID + lane * 8);
    accum8i(acc, hs, wself);

    int e0 = imax(0, imin(offs[v], Etot));
    int e1 = imax(e0, imin(offs[v + 1], Etot));
    for (int base = e0; base < e1; base += 64) {
        int cnt = imin(64, e1 - base);
        int sreg = 0; float wreg = 0.f;
        if (lane < cnt) {
            u32 s = (u32)csr[base + lane];
            s = (s < (u32)n) ? s : 0u;
            sreg = (int)s;
            wreg = dv * dinv[s] * H_INV_SCALE;
        }
        int j = 0;
        for (; j + 16 <= cnt; j += 16) {
            int ss[16]; float ww[16]; uint2 pp[16];
#pragma unroll
            for (int t = 0; t < 16; ++t) {
                ss[t] = __shfl(sreg, j + t);
                ww[t] = __shfl(wreg, j + t);
            }
#pragma unroll
            for (int t = 0; t < 16; ++t)
                pp[t] = *(const uint2*)(hq + (size_t)ss[t] * C_HID + lane * 8);
#pragma unroll
            for (int t = 0; t < 16; ++t) accum8i(acc, pp[t], ww[t]);
        }
        for (; j + 8 <= cnt; j += 8) {
            int ss[8]; float ww[8]; uint2 pp[8];
#pragma unroll
            for (int t = 0; t < 8; ++t) {
                ss[t] = __shfl(sreg, j + t);
                ww[t] = __shfl(wreg, j + t);
            }
#pragma unroll
            for (int t = 0; t < 8; ++t)
                pp[t] = *(const uint2*)(hq + (size_t)ss[t] * C_HID + lane * 8);
#pragma unroll
            for (int t = 0; t < 8; ++t) accum8i(acc, pp[t], ww[t]);
        }
        for (; j + 4 <= cnt; j += 4) {
            int ss[4]; float ww[4]; uint2 pp[4];
#pragma unroll
            for (int t = 0; t < 4; ++t) {
                ss[t] = __shfl(sreg, j + t);
                ww[t] = __shfl(wreg, j + t);
            }
#pragma unroll
            for (int t = 0; t < 4; ++t)
                pp[t] = *(const uint2*)(hq + (size_t)ss[t] * C_HID + lane * 8);
#pragma unroll
            for (int t = 0; t < 4; ++t) accum8i(acc, pp[t], ww[t]);
        }
        for (; j < cnt; ++j) {
            int sj = __shfl(sreg, j);
            float wj = __shfl(wreg, j);
            uint2 pj = *(const uint2*)(hq + (size_t)sj * C_HID + lane * 8);
            accum8i(acc, pj, wj);
        }
    }

    float4 ba = *(const float4*)(b1f + lane * 8);
    float4 bb = *(const float4*)(b1f + lane * 8 + 4);
    float r0 = fmaxf(acc[0] + ba.x, 0.f), r1 = fmaxf(acc[1] + ba.y, 0.f);
    float r2 = fmaxf(acc[2] + ba.z, 0.f), r3 = fmaxf(acc[3] + ba.w, 0.f);
    float r4 = fmaxf(acc[4] + bb.x, 0.f), r5 = fmaxf(acc[5] + bb.y, 0.f);
    float r6 = fmaxf(acc[6] + bb.z, 0.f), r7 = fmaxf(acc[7] + bb.w, 0.f);
    u32x4 o;
    o.x = (u32)f2bf(r0) | ((u32)f2bf(r1) << 16);
    o.y = (u32)f2bf(r2) | ((u32)f2bf(r3) << 16);
    o.z = (u32)f2bf(r4) | ((u32)f2bf(r5) << 16);
    o.w = (u32)f2bf(r6) | ((u32)f2bf(r7) << 16);
    // nontemporal: don't let the 50MB output stream evict h from L2
    __builtin_nontemporal_store(o, (u32x4*)(out + (size_t)v * C_HID + lane * 8));
}

// ---------------- agg2 + bias + log_softmax: bf16 h2, 24 edges in flight ----------------
__global__ __launch_bounds__(256) void k_agg2(
    const u16* __restrict__ h2, const int* __restrict__ csr, const int* __restrict__ offs,
    const float* __restrict__ dinv, const float* __restrict__ b2f,
    const int* __restrict__ flags, void* __restrict__ out, int n, int Etot) {
    int wave = threadIdx.x >> 6, lane = threadIdx.x & 63;
    int v = blockIdx.x * 4 + wave;
    if (v >= n) return;
    float dv = dinv[v];

    int g = lane / 10;
    int f4 = lane - g * 10;
    bool active = (g < 6);

    float4 acc = make_float4(0.f, 0.f, 0.f, 0.f);
    if (g == 0) {
        uint2 pv = *(const uint2*)(h2 + (size_t)v * C_OUT + f4 * 4);
        float w = dv * dv;
        acc.x = w * bf2f((u16)pv.x); acc.y = w * bf2f((u16)(pv.x >> 16));
        acc.z = w * bf2f((u16)pv.y); acc.w = w * bf2f((u16)(pv.y >> 16));
    }

    int e0 = imax(0, imin(offs[v], Etot));
    int e1 = imax(e0, imin(offs[v + 1], Etot));
    for (int base = e0; base < e1; base += 64) {
        int cnt = imin(64, e1 - base);
        int sreg = 0; float wreg = 0.f;
        if (lane < cnt) {
            u32 s = (u32)csr[base + lane];
            s = (s < (u32)n) ? s : 0u;
            sreg = (int)s;
            wreg = dv * dinv[s];
        }
        for (int j = 0; j < cnt; j += 24) {
            uint2 p[4]; float w4[4];
#pragma unroll
            for (int t = 0; t < 4; ++t) {
                int jj = j + t * 6 + g;
                int idx = imin(jj, cnt - 1);
                int sj = __shfl(sreg, idx);
                float wj = __shfl(wreg, idx);
                w4[t] = (active && jj < cnt) ? wj : 0.f;
                p[t] = make_uint2(0, 0);
                if (active) p[t] = *(const uint2*)(h2 + (size_t)sj * C_OUT + f4 * 4);
            }
#pragma unroll
            for (int t = 0; t < 4; ++t) {
                acc.x += w4[t] * bf2f((u16)p[t].x);
                acc.y += w4[t] * bf2f((u16)(p[t].x >> 16));
                acc.z += w4[t] * bf2f((u16)p[t].y);
                acc.w += w4[t] * bf2f((u16)(p[t].y >> 16));
            }
        }
    }

    float4 t;
    t.x = __shfl(acc.x, lane + 30); t.y = __shfl(acc.y, lane + 30);
    t.z = __shfl(acc.z, lane + 30); t.w = __shfl(acc.w, lane + 30);
    if (lane < 30) { acc.x += t.x; acc.y += t.y; acc.z += t.z; acc.w += t.w; }
    float4 t1, t2;
    t1.x = __shfl(acc.x, lane + 10); t1.y = __shfl(acc.y, lane + 10);
    t1.z = __shfl(acc.z, lane + 10); t1.w = __shfl(acc.w, lane + 10);
    t2.x = __shfl(acc.x, lane + 20); t2.y = __shfl(acc.y, lane + 20);
    t2.z = __shfl(acc.z, lane + 20); t2.w = __shfl(acc.w, lane + 20);
    if (lane < 10) {
        acc.x += t1.x + t2.x; acc.y += t1.y + t2.y;
        acc.z += t1.z + t2.z; acc.w += t1.w + t2.w;
        acc.x += b2f[f4 * 4 + 0]; acc.y += b2f[f4 * 4 + 1];
        acc.z += b2f[f4 * 4 + 2]; acc.w += b2f[f4 * 4 + 3];
    }

    float m = -1e30f;
    if (lane < 10) m = fmaxf(fmaxf(acc.x, acc.y), fmaxf(acc.z, acc.w));
    for (int off = 32; off > 0; off >>= 1) m = fmaxf(m, __shfl_xor(m, off));
    float s = 0.f;
    if (lane < 10)
        s = expf(acc.x - m) + expf(acc.y - m) + expf(acc.z - m) + expf(acc.w - m);
    for (int off = 32; off > 0; off >>= 1) s += __shfl_xor(s, off);
    if (lane < 10) {
        float ls = m + logf(s);
        if (flags[1]) {
            ushort4 o;
            o.x = f2bf(acc.x - ls); o.y = f2bf(acc.y - ls);
            o.z = f2bf(acc.z - ls); o.w = f2bf(acc.w - ls);
            *(ushort4*)((u16*)out + (size_t)v * C_OUT + f4 * 4) = o;
        } else {
            float4 o = make_float4(acc.x - ls, acc.y - ls, acc.z - ls, acc.w - ls);
            *(float4*)((float*)out + (size_t)v * C_OUT + f4 * 4) = o;
        }
    }
}

// ---------------- launch ----------------

extern "C" void kernel_launch(void* const* d_in, const int* in_sizes, int n_in,
                              void* d_out, int out_size, void* d_ws, size_t ws_size,
                              hipStream_t stream) {
    const void* x = d_in[0];
    const int* ei = (const int*)d_in[1];
    const void* W1 = d_in[2];
    const void* b1 = d_in[3];
    const void* W2 = d_in[4];
    const void* b2 = d_in[5];

    const int N = out_size / C_OUT;
    const int Mx = in_sizes[0] / C_IN;
    const int M = (N < Mx) ? N : Mx;
    const int ECAP = in_sizes[1];
    const int E = ECAP / 2;

    char* p = (char*)d_ws;
    size_t used = 0;
    auto carve = [&](size_t bytes) -> void* {
        void* r = (void*)p;
        size_t b = (bytes + 255) & ~(size_t)255;
        p += b; used += b;
        return r;
    };
    int* flags = (int*)carve(256);
    int* deg = (int*)carve((size_t)N * 4);
    int* cursor = (int*)carve((size_t)N * 4);
    float* dinv = (float*)carve((size_t)N * 4);
    int* offs = (int*)carve((size_t)(N + 1) * 4);
    u64* state = (u64*)carve(4096);
    int* csr = (int*)carve((size_t)E * 4);
    u16* w1t = (u16*)carve((size_t)C_HID * C_IN * 2);
    u16* w2t = (u16*)carve((size_t)64 * C_HID * 2);
    float* b1f = (float*)carve(C_HID * 4);
    float* b2f = (float*)carve(256);
    u16* bufA = (u16*)carve((size_t)N * C_HID * 2);   // hagg
    u16* bufB = (u16*)carve((size_t)N * C_HID * 2);   // h_i8, then h2 (bf16)
    if (used > ws_size) return;

    char* h_i8 = (char*)bufB;
    u16* hagg = bufA;
    u16* h2 = bufB;

    const int NB = (N + 255) / 256;
    const int EB = (E + 255) / 256;

    k_initprep<<<NB, 256, 0, stream>>>((const u32*)x, ei, W1, b1, W2, b2,
                                       flags, deg, cursor, state,
                                       w1t, w2t, b1f, b2f, N, NB);
    k_deg<<<EB, 256, 0, stream>>>(ei, flags, deg, E, ECAP, N);
    k_scan<<<NB, 256, 0, stream>>>(deg, dinv, offs, state, N, NB);
    k_sort<<<EB, 256, 0, stream>>>(ei, flags, offs, cursor, csr, E, ECAP, N);

    int nbx = (M + 63) / 64;
    k_gemm128<<<nbx * 4, 256, 0, stream>>>((const u16*)x, (const float*)x, flags,
                                           w1t, h_i8, M, C_IN, C_HID);

    k_agg1<<<(N + 3) / 4, 256, 0, stream>>>(h_i8, csr, offs, dinv, b1f, hagg, N, E);

    k_gemm64<<<(M + 127) / 128, 256, 0, stream>>>(hagg, w2t, h2, N, C_HID, C_OUT, C_OUT);

    k_agg2<<<(N + 3) / 4, 256, 0, stream>>>(h2, csr, offs, dinv, b2f, flags, d_out, N, E);
}

// Round 15
// 402.456 us; speedup vs baseline: 1.1499x; 1.0129x over previous
//
#include <hip/hip_runtime.h>

// GCN 2-layer forward on gfx950.
// R25: R24 with the swizzle KEY corrected: lr&3 -> (lr>>1)&3 (R24's key
//      contained the row parity bit already folded into the bank group, so
//      conflicts were bit-identical to unswizzled; R23 measured 0 conflicts
//      with (lr>>1)&3). Stage: LDS[row][slot]=chunk slot^((row>>1)&3) via
//      swizzled glds source / swizzled ds_write dest; read at
//      quad^((lrow>>1)&3). Everything else identical to R24/R21.

typedef unsigned int u32;
typedef unsigned short u16;
typedef unsigned long long u64;
typedef __bf16 bf16x8 __attribute__((ext_vector_type(8)));
typedef float f32x4 __attribute__((ext_vector_type(4)));
typedef u32 u32x4 __attribute__((ext_vector_type(4)));

#define C_IN 512
#define C_HID 512
#define C_OUT 40
#define H_SCALE 24.0f
#define H_INV_SCALE (1.0f / 24.0f)

__device__ __forceinline__ float bf2f(u16 u) {
    u32 x = ((u32)u) << 16;
    return __builtin_bit_cast(float, x);
}
__device__ __forceinline__ u16 f2bf(float f) {
    u32 x = __builtin_bit_cast(u32, f);
    x += 0x7fffu + ((x >> 16) & 1u);   // RNE
    return (u16)(x >> 16);
}
__device__ __forceinline__ char q8(float v) {
    float c = fminf(fmaxf(v * H_SCALE, -127.f), 127.f);
    return (char)__float2int_rn(c);
}
__device__ __forceinline__ u32 pk2(float a, float b) {
    u16 lo = __builtin_bit_cast(u16, (__bf16)a);
    u16 hi = __builtin_bit_cast(u16, (__bf16)b);
    return (u32)lo | ((u32)hi << 16);
}
__device__ __forceinline__ u32x4 pk8(float4 a, float4 b) {
    u32x4 r;
    r.x = pk2(a.x, a.y); r.y = pk2(a.z, a.w);
    r.z = pk2(b.x, b.y); r.w = pk2(b.z, b.w);
    return r;
}
__host__ __device__ __forceinline__ int imin(int a, int b) { return a < b ? a : b; }
__host__ __device__ __forceinline__ int imax(int a, int b) { return a > b ? a : b; }

__device__ __forceinline__ float ldf(const void* p, int i, int isbf) {
    return isbf ? bf2f(((const u16*)p)[i]) : ((const float*)p)[i];
}

// ---------------- initprep: flags + deg/cursor/state init + weight prep -----
__global__ __launch_bounds__(256) void k_initprep(
    const u32* __restrict__ x32, const int* __restrict__ ei,
    const void* __restrict__ W1, const void* __restrict__ b1,
    const void* __restrict__ W2, const void* __restrict__ b2,
    int* flags, int* deg, int* cursor, u64* state,
    u16* __restrict__ w1t, u16* __restrict__ w2t,
    float* __restrict__ b1f, float* __restrict__ b2f,
    int n, int nchunks) {
    __shared__ float tile[64][65];
    __shared__ int s_flags[2];
    int tid = threadIdx.x;
    if (tid < 64) {
        int lane = tid;
        int z = (ei[2 * lane + 1] == 0) ? 1 : 0;
        u32 e = (x32[lane] >> 7) & 0xff;
        int v = (e >= 110 && e <= 133) ? 1 : 0;
        unsigned long long bz = __ballot(z);
        unsigned long long bv = __ballot(v);
        if (lane == 0) {
            s_flags[0] = (__popcll(bz) == 64) ? 2 : 1;
            s_flags[1] = (__popcll(bv) >= 48) ? 1 : 0;
        }
    }
    __syncthreads();
    int isbf = s_flags[1];
    int i0 = blockIdx.x * 256 + tid;
    int stride = gridDim.x * 256;
    if (blockIdx.x == 0 && tid == 0) { flags[0] = s_flags[0]; flags[1] = isbf; }
    if (i0 < n) { deg[i0] = 1; cursor[i0] = 0; }       // self-loop
    if (i0 < nchunks) state[i0] = 0ULL;
    if (blockIdx.x < 64) {
        int t = blockIdx.x;
        int tr = t >> 3, tc = t & 7;
        int rr = tid >> 2, cq = (tid & 3) * 16;
#pragma unroll
        for (int c = 0; c < 16; ++c)
            tile[cq + c][rr] = ldf(W1, (tr * 64 + rr) * 512 + tc * 64 + cq + c, isbf);
        __syncthreads();
#pragma unroll
        for (int c = 0; c < 16; ++c)
            w1t[(size_t)(tc * 64 + rr) * 512 + tr * 64 + cq + c] = f2bf(tile[rr][cq + c]);
    }
    for (int i = i0; i < 64 * 512; i += stride) {
        int nn = i >> 9, k = i & 511;
        w2t[i] = (nn < C_OUT) ? f2bf(ldf(W2, k * C_OUT + nn, isbf)) : (u16)0;
    }
    if (i0 < C_HID) b1f[i0] = ldf(b1, i0, isbf);
    if (i0 < C_OUT) b2f[i0] = ldf(b2, i0, isbf);
}

__global__ void k_deg(const int* __restrict__ ei, const int* __restrict__ flags,
                      int* deg, int E, int ecap, int n) {
    int e = blockIdx.x * 256 + threadIdx.x;
    if (e >= E) return;
    int st = flags[0];
    int cap = ecap * st - 1;
    u32 d = (u32)ei[imin((E + e) * st, cap)];
    if (d < (u32)n) atomicAdd(&deg[d], 1);
}

// ---------------- single-kernel scan: dinv + exclusive offs (lookback) ------
__global__ __launch_bounds__(256) void k_scan(
    const int* __restrict__ deg, float* __restrict__ dinv, int* __restrict__ offs,
    u64* state, int n, int nchunks) {
    __shared__ int sh[256];
    __shared__ int s_prefix;
    int tid = threadIdx.x;
    int c = blockIdx.x;
    int i = c * 256 + tid;
    int dv = (i < n) ? deg[i] : 1;
    if (i < n) dinv[i] = rsqrtf((float)imax(dv, 1));
    int v = (i < n) ? dv - 1 : 0;
    sh[tid] = v;
    __syncthreads();
    for (int d = 1; d < 256; d <<= 1) {
        int add = (tid >= d) ? sh[tid - d] : 0;
        __syncthreads();
        sh[tid] += add;
        __syncthreads();
    }
    int total = sh[255];
    if (tid == 0) {
        atomicExch(&state[c], (1ULL << 62) | (u64)(u32)total);
        long long prefix = 0;
        int cc = c - 1;
        while (cc >= 0) {
            u64 s;
            do { s = atomicAdd(&state[cc], 0ULL); } while (s == 0ULL);
            prefix += (long long)(u32)s;
            if (s >> 63) break;
            --cc;
        }
        atomicExch(&state[c], (1ULL << 63) | (u64)(u32)(prefix + total));
        s_prefix = (int)prefix;
        if (c == nchunks - 1) offs[n] = (int)(prefix + total);
    }
    __syncthreads();
    int pfx = s_prefix;
    if (i < n) offs[i] = pfx + sh[tid] - v;   // exclusive
}

__global__ void k_sort(const int* __restrict__ ei, const int* __restrict__ flags,
                       const int* __restrict__ offs, int* cursor, int* csr,
                       int E, int ecap, int n) {
    int e = blockIdx.x * 256 + threadIdx.x;
    if (e >= E) return;
    int st = flags[0];
    int cap = ecap * st - 1;
    u32 d = (u32)ei[imin((E + e) * st, cap)];
    u32 s = (u32)ei[imin(e * st, cap)];
    if (d < (u32)n && s < (u32)n) {
        int pos = offs[d] + atomicAdd(&cursor[(int)d], 1);
        if ((u32)pos < (u32)E) csr[pos] = (int)s;
    }
}

// ---------------- GEMM1: 64x128 tile, BK=64, split-half LDS + XOR swizzle ---
// LDS[row][slot] = chunk slot^((row>>1)&3) (chunk = 16B). fp32 A: swizzled
// ds_write dest; bf16 A + B glds: swizzled global source. Fragment reads at
// slot quad^((lrow>>1)&3). (R23 measured 0 conflicts with this key.)
typedef __attribute__((address_space(1))) const u32 glds_src;
typedef __attribute__((address_space(3))) u32 glds_dst;

__global__ __launch_bounds__(256) void k_gemm128(
    const u16* __restrict__ xbf, const float* __restrict__ xf32,
    const int* __restrict__ flags, const u16* __restrict__ Bt,
    char* __restrict__ C, int M, int K, int ldc) {
    int isbf = flags[1];
    __shared__ __align__(16) u16 As0[64 * 32], As1[64 * 32];
    __shared__ __align__(16) u16 Bs0[128 * 32], Bs1[128 * 32];
    int tid = threadIdx.x;
    int wave = tid >> 6, lane = tid & 63;
    int quad = lane >> 4, lrow = lane & 15;
    int wrow = (wave & 1) * 32, wcol = (wave >> 1) * 64;

    int nwg = gridDim.x;
    int id = blockIdx.x;
    int q = nwg >> 3, r = nwg & 7;
    int xcd = id & 7, j8 = id >> 3;
    int wg = (xcd < r ? xcd * (q + 1) : r * (q + 1) + (xcd - r) * q) + j8;
    int row0 = (wg >> 2) * 64;
    int n0 = (wg & 3) * 128;

    int lr = lane >> 2;            // 0..15 row within 16-row staging group
    int lcq = lane & 3;            // 16B chunk slot
    int key = (lr >> 1) & 3;       // swizzle key (row bit NOT in bank parity)
    int lc = (lane & 3) * 8;       // linear col elems (fp32 A source)
    int scs = (lcq ^ key) * 8;     // swizzled source col elems (glds paths)
    int ar = row0 + wave * 16 + lr;
    int br = n0 + wave * 32 + lr;
    u16* As0_w = As0 + (wave * 16) * 32;
    u16* As1_w = As1 + (wave * 16) * 32;
    u16* Bs0_w = Bs0 + (wave * 32) * 32;
    u16* Bs1_w = Bs1 + (wave * 32) * 32;

    f32x4 acc[2][4] = {};
    int kTiles = K >> 6;   // BK=64
    int a0 = imin(ar, M - 1);
    int rdq = (quad ^ ((lrow >> 1) & 3)) * 8;   // swizzled read slot (elems)
    for (int kt = 0; kt < kTiles; ++kt) {
        int k0 = kt * 64;
        if (isbf) {
            const u16* gA0 = xbf + (size_t)a0 * K + k0 + scs;
            __builtin_amdgcn_global_load_lds((glds_src*)gA0, (glds_dst*)As0_w, 16, 0, 0);
            __builtin_amdgcn_global_load_lds((glds_src*)(gA0 + 32), (glds_dst*)As1_w, 16, 0, 0);
        } else {
            const float* f0 = xf32 + (size_t)a0 * K + k0 + lc;
            float4 u0 = *(const float4*)(f0);
            float4 u1 = *(const float4*)(f0 + 4);
            float4 u2 = *(const float4*)(f0 + 32);
            float4 u3 = *(const float4*)(f0 + 36);
            int dsl = (lcq ^ key) * 8;   // swizzled ds_write dest slot
            *(u32x4*)(As0_w + lr * 32 + dsl) = pk8(u0, u1);
            *(u32x4*)(As1_w + lr * 32 + dsl) = pk8(u2, u3);
        }
        const u16* gB0 = Bt + (size_t)br * K + k0 + scs;
        const u16* gB1 = Bt + (size_t)(br + 16) * K + k0 + scs;
        __builtin_amdgcn_global_load_lds((glds_src*)gB0, (glds_dst*)Bs0_w, 16, 0, 0);
        __builtin_amdgcn_global_load_lds((glds_src*)gB1, (glds_dst*)(Bs0_w + 16 * 32), 16, 0, 0);
        __builtin_amdgcn_global_load_lds((glds_src*)(gB0 + 32), (glds_dst*)Bs1_w, 16, 0, 0);
        __builtin_amdgcn_global_load_lds((glds_src*)(gB1 + 32), (glds_dst*)(Bs1_w + 16 * 32), 16, 0, 0);
        __syncthreads();
#pragma unroll
        for (int ko = 0; ko < 2; ++ko) {
            const u16* Asrc = ko ? As1 : As0;
            const u16* Bsrc = ko ? Bs1 : Bs0;
            bf16x8 af[2], bfr[4];
#pragma unroll
            for (int i = 0; i < 2; ++i)
                af[i] = *(const bf16x8*)(Asrc + (wrow + i * 16 + lrow) * 32 + rdq);
#pragma unroll
            for (int j = 0; j < 4; ++j)
                bfr[j] = *(const bf16x8*)(Bsrc + (wcol + j * 16 + lrow) * 32 + rdq);
#pragma unroll
            for (int i = 0; i < 2; ++i)
#pragma unroll
                for (int j = 0; j < 4; ++j)
                    acc[i][j] = __builtin_amdgcn_mfma_f32_16x16x32_bf16(af[i], bfr[j],
                                                                        acc[i][j], 0, 0, 0);
        }
        __syncthreads();
    }
#pragma unroll
    for (int i = 0; i < 2; ++i)
#pragma unroll
        for (int j = 0; j < 4; ++j)
#pragma unroll
            for (int r2 = 0; r2 < 4; ++r2) {
                int row = row0 + wrow + i * 16 + quad * 4 + r2;
                int col = n0 + wcol + j * 16 + lrow;
                if (row < M) C[(size_t)row * ldc + col] = q8(acc[i][j][r2]);
            }
}

// ---------------- GEMM2: w2t-in-LDS, barrier-free A stream, bf16 out --------
#define B2ROW 520
__global__ __launch_bounds__(256) void k_gemm64(
    const u16* __restrict__ A, const u16* __restrict__ Bt, u16* __restrict__ Cout,
    int M, int K, int Ncols, int ldc) {
    __shared__ __align__(16) u16 Bsh[48 * B2ROW];
    int tid = threadIdx.x;
    int wave = tid >> 6, lane = tid & 63;
    int quad = lane >> 4, lrow = lane & 15;

    for (int i = tid; i < 48 * 64; i += 256) {
        int rw = i >> 6, cv = (i & 63) * 8;
        *(uint4*)(Bsh + rw * B2ROW + cv) = *(const uint4*)(Bt + (size_t)rw * 512 + cv);
    }
    __syncthreads();

    int row0 = blockIdx.x * 128 + wave * 32;
    int r0 = imin(row0 + lrow, M - 1);
    int r1 = imin(row0 + 16 + lrow, M - 1);
    const u16* a0p = A + (size_t)r0 * K + quad * 8;
    const u16* a1p = A + (size_t)r1 * K + quad * 8;
    const u16* b0p = Bsh + (0 * 16 + lrow) * B2ROW + quad * 8;
    const u16* b1p = Bsh + (1 * 16 + lrow) * B2ROW + quad * 8;
    const u16* b2p = Bsh + (2 * 16 + lrow) * B2ROW + quad * 8;

    f32x4 c00 = {}, c01 = {}, c02 = {};
    f32x4 c10 = {}, c11 = {}, c12 = {};
#pragma unroll 4
    for (int k0 = 0; k0 < C_HID; k0 += 32) {
        bf16x8 a0 = *(const bf16x8*)(a0p + k0);
        bf16x8 a1 = *(const bf16x8*)(a1p + k0);
        bf16x8 b0 = *(const bf16x8*)(b0p + k0);
        bf16x8 b1 = *(const bf16x8*)(b1p + k0);
        bf16x8 b2 = *(const bf16x8*)(b2p + k0);
        c00 = __builtin_amdgcn_mfma_f32_16x16x32_bf16(a0, b0, c00, 0, 0, 0);
        c01 = __builtin_amdgcn_mfma_f32_16x16x32_bf16(a0, b1, c01, 0, 0, 0);
        c02 = __builtin_amdgcn_mfma_f32_16x16x32_bf16(a0, b2, c02, 0, 0, 0);
        c10 = __builtin_amdgcn_mfma_f32_16x16x32_bf16(a1, b0, c10, 0, 0, 0);
        c11 = __builtin_amdgcn_mfma_f32_16x16x32_bf16(a1, b1, c11, 0, 0, 0);
        c12 = __builtin_amdgcn_mfma_f32_16x16x32_bf16(a1, b2, c12, 0, 0, 0);
    }
    f32x4 cc[2][3] = {{c00, c01, c02}, {c10, c11, c12}};
#pragma unroll
    for (int i = 0; i < 2; ++i)
#pragma unroll
        for (int t = 0; t < 3; ++t)
#pragma unroll
            for (int r = 0; r < 4; ++r) {
                int row = row0 + i * 16 + quad * 4 + r;
                int col = t * 16 + lrow;
                if (row < M && col < Ncols)
                    Cout[(size_t)row * ldc + col] = f2bf(cc[i][t][r]);
            }
}

// ---------------- agg1: hagg = ReLU(Anorm*h + b1), int8 in, bf16 out ----------------
__device__ __forceinline__ void accum8i(float* acc, uint2 p, float w) {
    int lo = (int)p.x, hi = (int)p.y;
    acc[0] += w * (float)(signed char)(lo);
    acc[1] += w * (float)(signed char)(lo >> 8);
    acc[2] += w * (float)(signed char)(lo >> 16);
    acc[3] += w * (float)(signed char)(lo >> 24);
    acc[4] += w * (float)(signed char)(hi);
    acc[5] += w * (float)(signed char)(hi >> 8);
    acc[6] += w * (float)(signed char)(hi >> 16);
    acc[7] += w * (float)(signed char)(hi >> 24);
}

__global__ __launch_bounds__(256) void k_agg1(
    const char* __restrict__ hq, const int* __restrict__ csr, const int* __restrict__ offs,
    const float* __restrict__ dinv, const float* __restrict__ b1f,
    u16* __restrict__ out, int n, int Etot) {
    int wave = threadIdx.x >> 6, lane = threadIdx.x & 63;
    int v = blockIdx.x * 4 + wave;
    if (v >= n) return;
    float dv = dinv[v];
    float wself = dv * dv * H_INV_SCALE;

    float acc[8] = {0.f, 0.f, 0.f, 0.f, 0.f, 0.f, 0.f, 0.f};
    uint2 hs = *(const uint2*)(hq + (size_t)v * C_HID + lane * 8);
    accum8i(acc, hs, wself);

    int e0 = imax(0, imin(offs[v], Etot));
    int e1 = imax(e0, imin(offs[v + 1], Etot));
    for (int base = e0; base < e1; base += 64) {
        int cnt = imin(64, e1 - base);
        int sreg = 0; float wreg = 0.f;
        if (lane < cnt) {
            u32 s = (u32)csr[base + lane];
            s = (s < (u32)n) ? s : 0u;
            sreg = (int)s;
            wreg = dv * dinv[s] * H_INV_SCALE;
        }
        int j = 0;
        for (; j + 16 <= cnt; j += 16) {
            int ss[16]; float ww[16]; uint2 pp[16];
#pragma unroll
            for (int t = 0; t < 16; ++t) {
                ss[t] = __shfl(sreg, j + t);
                ww[t] = __shfl(wreg, j + t);
            }
#pragma unroll
            for (int t = 0; t < 16; ++t)
                pp[t] = *(const uint2*)(hq + (size_t)ss[t] * C_HID + lane * 8);
#pragma unroll
            for (int t = 0; t < 16; ++t) accum8i(acc, pp[t], ww[t]);
        }
        for (; j + 8 <= cnt; j += 8) {
            int ss[8]; float ww[8]; uint2 pp[8];
#pragma unroll
            for (int t = 0; t < 8; ++t) {
                ss[t] = __shfl(sreg, j + t);
                ww[t] = __shfl(wreg, j + t);
            }
#pragma unroll
            for (int t = 0; t < 8; ++t)
                pp[t] = *(const uint2*)(hq + (size_t)ss[t] * C_HID + lane * 8);
#pragma unroll
            for (int t = 0; t < 8; ++t) accum8i(acc, pp[t], ww[t]);
        }
        for (; j + 4 <= cnt; j += 4) {
            int ss[4]; float ww[4]; uint2 pp[4];
#pragma unroll
            for (int t = 0; t < 4; ++t) {
                ss[t] = __shfl(sreg, j + t);
                ww[t] = __shfl(wreg, j + t);
            }
#pragma unroll
            for (int t = 0; t < 4; ++t)
                pp[t] = *(const uint2*)(hq + (size_t)ss[t] * C_HID + lane * 8);
#pragma unroll
            for (int t = 0; t < 4; ++t) accum8i(acc, pp[t], ww[t]);
        }
        for (; j < cnt; ++j) {
            int sj = __shfl(sreg, j);
            float wj = __shfl(wreg, j);
            uint2 pj = *(const uint2*)(hq + (size_t)sj * C_HID + lane * 8);
            accum8i(acc, pj, wj);
        }
    }

    float4 ba = *(const float4*)(b1f + lane * 8);
    float4 bb = *(const float4*)(b1f + lane * 8 + 4);
    float r0 = fmaxf(acc[0] + ba.x, 0.f), r1 = fmaxf(acc[1] + ba.y, 0.f);
    float r2 = fmaxf(acc[2] + ba.z, 0.f), r3 = fmaxf(acc[3] + ba.w, 0.f);
    float r4 = fmaxf(acc[4] + bb.x, 0.f), r5 = fmaxf(acc[5] + bb.y, 0.f);
    float r6 = fmaxf(acc[6] + bb.z, 0.f), r7 = fmaxf(acc[7] + bb.w, 0.f);
    u32x4 o;
    o.x = (u32)f2bf(r0) | ((u32)f2bf(r1) << 16);
    o.y = (u32)f2bf(r2) | ((u32)f2bf(r3) << 16);
    o.z = (u32)f2bf(r4) | ((u32)f2bf(r5) << 16);
    o.w = (u32)f2bf(r6) | ((u32)f2bf(r7) << 16);
    // nontemporal: don't let the 50MB output stream evict h from L2
    __builtin_nontemporal_store(o, (u32x4*)(out + (size_t)v * C_HID + lane * 8));
}

// ---------------- agg2 + bias + log_softmax: bf16 h2, 24 edges in flight ----------------
__global__ __launch_bounds__(256) void k_agg2(
    const u16* __restrict__ h2, const int* __restrict__ csr, const int* __restrict__ offs,
    const float* __restrict__ dinv, const float* __restrict__ b2f,
    const int* __restrict__ flags, void* __restrict__ out, int n, int Etot) {
    int wave = threadIdx.x >> 6, lane = threadIdx.x & 63;
    int v = blockIdx.x * 4 + wave;
    if (v >= n) return;
    float dv = dinv[v];

    int g = lane / 10;
    int f4 = lane - g * 10;
    bool active = (g < 6);

    float4 acc = make_float4(0.f, 0.f, 0.f, 0.f);
    if (g == 0) {
        uint2 pv = *(const uint2*)(h2 + (size_t)v * C_OUT + f4 * 4);
        float w = dv * dv;
        acc.x = w * bf2f((u16)pv.x); acc.y = w * bf2f((u16)(pv.x >> 16));
        acc.z = w * bf2f((u16)pv.y); acc.w = w * bf2f((u16)(pv.y >> 16));
    }

    int e0 = imax(0, imin(offs[v], Etot));
    int e1 = imax(e0, imin(offs[v + 1], Etot));
    for (int base = e0; base < e1; base += 64) {
        int cnt = imin(64, e1 - base);
        int sreg = 0; float wreg = 0.f;
        if (lane < cnt) {
            u32 s = (u32)csr[base + lane];
            s = (s < (u32)n) ? s : 0u;
            sreg = (int)s;
            wreg = dv * dinv[s];
        }
        for (int j = 0; j < cnt; j += 24) {
            uint2 p[4]; float w4[4];
#pragma unroll
            for (int t = 0; t < 4; ++t) {
                int jj = j + t * 6 + g;
                int idx = imin(jj, cnt - 1);
                int sj = __shfl(sreg, idx);
                float wj = __shfl(wreg, idx);
                w4[t] = (active && jj < cnt) ? wj : 0.f;
                p[t] = make_uint2(0, 0);
                if (active) p[t] = *(const uint2*)(h2 + (size_t)sj * C_OUT + f4 * 4);
            }
#pragma unroll
            for (int t = 0; t < 4; ++t) {
                acc.x += w4[t] * bf2f((u16)p[t].x);
                acc.y += w4[t] * bf2f((u16)(p[t].x >> 16));
                acc.z += w4[t] * bf2f((u16)p[t].y);
                acc.w += w4[t] * bf2f((u16)(p[t].y >> 16));
            }
        }
    }

    float4 t;
    t.x = __shfl(acc.x, lane + 30); t.y = __shfl(acc.y, lane + 30);
    t.z = __shfl(acc.z, lane + 30); t.w = __shfl(acc.w, lane + 30);
    if (lane < 30) { acc.x += t.x; acc.y += t.y; acc.z += t.z; acc.w += t.w; }
    float4 t1, t2;
    t1.x = __shfl(acc.x, lane + 10); t1.y = __shfl(acc.y, lane + 10);
    t1.z = __shfl(acc.z, lane + 10); t1.w = __shfl(acc.w, lane + 10);
    t2.x = __shfl(acc.x, lane + 20); t2.y = __shfl(acc.y, lane + 20);
    t2.z = __shfl(acc.z, lane + 20); t2.w = __shfl(acc.w, lane + 20);
    if (lane < 10) {
        acc.x += t1.x + t2.x; acc.y += t1.y + t2.y;
        acc.z += t1.z + t2.z; acc.w += t1.w + t2.w;
        acc.x += b2f[f4 * 4 + 0]; acc.y += b2f[f4 * 4 + 1];
        acc.z += b2f[f4 * 4 + 2]; acc.w += b2f[f4 * 4 + 3];
    }

    float m = -1e30f;
    if (lane < 10) m = fmaxf(fmaxf(acc.x, acc.y), fmaxf(acc.z, acc.w));
    for (int off = 32; off > 0; off >>= 1) m = fmaxf(m, __shfl_xor(m, off));
    float s = 0.f;
    if (lane < 10)
        s = expf(acc.x - m) + expf(acc.y - m) + expf(acc.z - m) + expf(acc.w - m);
    for (int off = 32; off > 0; off >>= 1) s += __shfl_xor(s, off);
    if (lane < 10) {
        float ls = m + logf(s);
        if (flags[1]) {
            ushort4 o;
            o.x = f2bf(acc.x - ls); o.y = f2bf(acc.y - ls);
            o.z = f2bf(acc.z - ls); o.w = f2bf(acc.w - ls);
            *(ushort4*)((u16*)out + (size_t)v * C_OUT + f4 * 4) = o;
        } else {
            float4 o = make_float4(acc.x - ls, acc.y - ls, acc.z - ls, acc.w - ls);
            *(float4*)((float*)out + (size_t)v * C_OUT + f4 * 4) = o;
        }
    }
}

// ---------------- launch ----------------

extern "C" void kernel_launch(void* const* d_in, const int* in_sizes, int n_in,
                              void* d_out, int out_size, void* d_ws, size_t ws_size,
                              hipStream_t stream) {
    const void* x = d_in[0];
    const int* ei = (const int*)d_in[1];
    const void* W1 = d_in[2];
    const void* b1 = d_in[3];
    const void* W2 = d_in[4];
    const void* b2 = d_in[5];

    const int N = out_size / C_OUT;
    const int Mx = in_sizes[0] / C_IN;
    const int M = (N < Mx) ? N : Mx;
    const int ECAP = in_sizes[1];
    const int E = ECAP / 2;

    char* p = (char*)d_ws;
    size_t used = 0;
    auto carve = [&](size_t bytes) -> void* {
        void* r = (void*)p;
        size_t b = (bytes + 255) & ~(size_t)255;
        p += b; used += b;
        return r;
    };
    int* flags = (int*)carve(256);
    int* deg = (int*)carve((size_t)N * 4);
    int* cursor = (int*)carve((size_t)N * 4);
    float* dinv = (float*)carve((size_t)N * 4);
    int* offs = (int*)carve((size_t)(N + 1) * 4);
    u64* state = (u64*)carve(4096);
    int* csr = (int*)carve((size_t)E * 4);
    u16* w1t = (u16*)carve((size_t)C_HID * C_IN * 2);
    u16* w2t = (u16*)carve((size_t)64 * C_HID * 2);
    float* b1f = (float*)carve(C_HID * 4);
    float* b2f = (float*)carve(256);
    u16* bufA = (u16*)carve((size_t)N * C_HID * 2);   // hagg
    u16* bufB = (u16*)carve((size_t)N * C_HID * 2);   // h_i8, then h2 (bf16)
    if (used > ws_size) return;

    char* h_i8 = (char*)bufB;
    u16* hagg = bufA;
    u16* h2 = bufB;

    const int NB = (N + 255) / 256;
    const int EB = (E + 255) / 256;

    k_initprep<<<NB, 256, 0, stream>>>((const u32*)x, ei, W1, b1, W2, b2,
                                       flags, deg, cursor, state,
                                       w1t, w2t, b1f, b2f, N, NB);
    k_deg<<<EB, 256, 0, stream>>>(ei, flags, deg, E, ECAP, N);
    k_scan<<<NB, 256, 0, stream>>>(deg, dinv, offs, state, N, NB);
    k_sort<<<EB, 256, 0, stream>>>(ei, flags, offs, cursor, csr, E, ECAP, N);

    int nbx = (M + 63) / 64;
    k_gemm128<<<nbx * 4, 256, 0, stream>>>((const u16*)x, (const float*)x, flags,
                                           w1t, h_i8, M, C_IN, C_HID);

    k_agg1<<<(N + 3) / 4, 256, 0, stream>>>(h_i8, csr, offs, dinv, b1f, hagg, N, E);

    k_gemm64<<<(M + 127) / 128, 256, 0, stream>>>(hagg, w2t, h2, N, C_HID, C_OUT, C_OUT);

    k_agg2<<<(N + 3) / 4, 256, 0, stream>>>(h2, csr, offs, dinv, b2f, flags, d_out, N, E);
}